// Round 2
// baseline (229.108 us; speedup 1.0000x reference)
//
#include <hip/hip_runtime.h>

// FWHT over last dim (4096) of [8192, 4096] fp32, normalized by 1/64.
// H_4096 factored as three FWHT-16 passes over bit-groups
//   G1={0,1,10,11} (register pass, fully-coalesced float4 loads)
//   G2={2,3,4,5}   (LDS pass)
//   G3={6,7,8,9}   (LDS pass, coalesced dword stores)
// Stage order across groups differs from the reference's LSB->MSB order only
// in fp rounding (stages commute algebraically); error ~1e-6 vs 0.12 thresh.
// One block of 256 threads per row.

#define N        4096
#define THREADS  256
// LDS addr = d0 + D1*d1 + D2*d2 + D3*d3, digits d0=bits0-1, d1=bits2-5,
// d2=bits6-9, d3=bits10-11.
// D1=4  -> phase-3 lanes (vary d0,d1) cover banks 0..63 -> 2-way (free).
// D2=76 -> 76%32=12: phase-2 lanes (vary d0,d2) cover all 32 banks 2x (free).
// D3=1204 (>= 3+4*15+76*15+1, mult of 4 for float4 alignment).
#define D1 4
#define D2 76
#define D3 1204
#define LDS_FLOATS (3 + D1*15 + D2*15 + D3*3 + 1)   // 4816 floats = 19264 B

__device__ __forceinline__ void fwht16(float v[16]) {
#pragma unroll
    for (int s = 1; s < 16; s <<= 1) {
#pragma unroll
        for (int k = 0; k < 16; k++) {
            if ((k & s) == 0) {
                float a = v[k];
                float b = v[k + s];
                v[k]     = a + b;
                v[k + s] = a - b;
            }
        }
    }
}

__global__ __launch_bounds__(THREADS)
void FWHT_83476984365427_kernel(const float* __restrict__ x,
                                float* __restrict__ out,
                                int nrows) {
    __shared__ float lds[LDS_FLOATS];

    const int row = blockIdx.x;
    if (row >= nrows) return;

    const float* __restrict__ xr  = x   + (size_t)row * N;
    float* __restrict__       otr = out + (size_t)row * N;
    const int t = threadIdx.x;

    float v[16];

    // ---- Phase 1: bits {0,1,10,11}. Thread t holds e = c*1024 + t*4 + j.
    // Load: float4 index c*256 + t -> each wave instr reads 1 KiB contiguous.
    {
        const float4* xv = (const float4*)xr;
#pragma unroll
        for (int c = 0; c < 4; c++) {
            float4 f = xv[c * 256 + t];
            v[4 * c + 0] = f.x;
            v[4 * c + 1] = f.y;
            v[4 * c + 2] = f.z;
            v[4 * c + 3] = f.w;
        }
    }
    fwht16(v);   // local idx = 4*c + j -> stages hit global bits 0,1,10,11

    // LDS write: d1 = t&15, d2 = t>>4; per c one aligned float4 (d0 contig).
    {
        const int d1 = t & 15;
        const int d2 = t >> 4;
        float* dst = &lds[D1 * d1 + D2 * d2];
#pragma unroll
        for (int c = 0; c < 4; c++) {
            float4 f;
            f.x = v[4 * c + 0];
            f.y = v[4 * c + 1];
            f.z = v[4 * c + 2];
            f.w = v[4 * c + 3];
            *(float4*)(dst + D3 * c) = f;
        }
    }
    __syncthreads();

    // ---- Phase 2: bits {2,3,4,5}. Thread owns fixed (d0,d2,d3), varies d1.
    {
        const int d0 = t & 3;
        const int d2 = (t >> 2) & 15;
        const int d3 = t >> 6;
        const int base = d0 + D2 * d2 + D3 * d3;
#pragma unroll
        for (int k = 0; k < 16; k++) v[k] = lds[base + D1 * k];
        fwht16(v);
        // Exclusive ownership of these 16 addresses -> no barrier before write.
#pragma unroll
        for (int k = 0; k < 16; k++) lds[base + D1 * k] = v[k];
    }
    __syncthreads();

    // ---- Phase 3: bits {6,7,8,9}. Thread owns fixed (d0,d1,d3), varies d2.
    {
        const int d0 = t & 3;
        const int d1 = (t >> 2) & 15;
        const int d3 = t >> 6;
        const int base = d0 + D1 * d1 + D3 * d3;
#pragma unroll
        for (int k = 0; k < 16; k++) v[k] = lds[base + D2 * k];
        fwht16(v);
        const float scale = 1.0f / 64.0f;   // 1/sqrt(4096), exact
        // Output element e = 64*k + (t&63) + 1024*(t>>6):
        // lanes consecutive -> 256 B contiguous per wave store.
        const int eb = (t & 63) + 1024 * (t >> 6);
#pragma unroll
        for (int k = 0; k < 16; k++) {
            __builtin_nontemporal_store(v[k] * scale, &otr[64 * k + eb]);
        }
    }
}

extern "C" void kernel_launch(void* const* d_in, const int* in_sizes, int n_in,
                              void* d_out, int out_size, void* d_ws, size_t ws_size,
                              hipStream_t stream) {
    (void)n_in; (void)d_ws; (void)ws_size; (void)out_size;
    const float* x = (const float*)d_in[0];
    float* out = (float*)d_out;
    const int nrows = in_sizes[0] / N;
    dim3 grid(nrows);
    dim3 block(THREADS);
    FWHT_83476984365427_kernel<<<grid, block, 0, stream>>>(x, out, nrows);
}